// Round 6
// baseline (3411.130 us; speedup 1.0000x reference)
//
#include <hip/hip_runtime.h>
#include <hip/hip_bf16.h>

typedef __hip_bfloat16 bf16;
typedef __attribute__((ext_vector_type(8))) short short8;
typedef __attribute__((ext_vector_type(4))) float float4v;

#define TPB 256
#define IMGB 18432      // A-image bytes per (img, cb): 256 px * 72 B rows
#define ROWB 72

__device__ __forceinline__ short f2bs(float v) {
    __hip_bfloat16 h = __float2bfloat16(v);
    return *reinterpret_cast<short*>(&h);
}
__device__ __forceinline__ float bs2f(short s) {
    union { unsigned u; float f; } c; c.u = ((unsigned)(unsigned short)s) << 16; return c.f;
}

// async global->LDS DMA: 16B/lane, LDS dest = wave-uniform base + lane*16
__device__ __forceinline__ void gl_lds16(const void* g, void* l) {
    __builtin_amdgcn_global_load_lds(
        (const __attribute__((address_space(1))) void*)g,
        (__attribute__((address_space(3))) void*)l, 16, 0, 0);
}

// ---------------------------------------------------------------------------
// Weights -> bf16 DMA images [nb][cb][g(=dy)][GRPB]: rows (tap_in*64+nn)*72B,
// 32 ci + 4 pad shorts (pads never read; stride for bank decorrelation).
// K=3: 3 groups of 3 taps, GRPB=14336 (raw 13824). K=1: 1 group, GRPB=5120.
// ---------------------------------------------------------------------------
__global__ void wxform_kernel(const float* __restrict__ w, bf16* __restrict__ dst,
                              int Cin, int K, int total8) {
    int i = blockIdx.x * TPB + threadIdx.x;
    if (i >= total8) return;
    const int NGR  = (K == 3) ? 3 : 1;
    const int GRPB = (K == 3) ? 14336 : 5120;
    const int RAWB = (K == 3) ? 13824 : 4608;
    const int TAPS = K * K;
    const int nc   = Cin >> 5;
    long b   = (long)i * 16;
    int  gl  = (int)(b / GRPB);
    int  off = (int)(b - (long)gl * GRPB);
    int  g   = gl % NGR; int t2 = gl / NGR;
    int  cb  = t2 % nc;  int nb = t2 / nc;
    short8 o;
#pragma unroll
    for (int j = 0; j < 8; ++j) {
        int ob = off + j * 2;
        float v = 0.f;
        if (ob < RAWB) {
            int r  = ob / 72;
            int ci = (ob - r * 72) >> 1;
            if (ci < 32) {
                int tap = g * 3 + (r >> 6);
                int nn  = r & 63;
                v = w[((size_t)(nb * 64 + nn) * Cin + (cb * 32 + ci)) * TAPS + tap];
            }
        }
        o[j] = f2bs(v);
    }
    *(short8*)((char*)dst + b) = o;
}

// obj_maps f32 (n,64,256) -> bf16 DMA images (n,2cb,256px,36ci)
__global__ void objcvt_kernel(const float* __restrict__ om, bf16* __restrict__ dst) {
    int gid = blockIdx.x * TPB + threadIdx.x;   // (n, cb, px)
    int px = gid & 255;
    int cb = (gid >> 8) & 1;
    int n  = gid >> 9;
    const float* src = om + ((size_t)n * 64 + cb * 32) * 256 + px;
    char* drow = (char*)dst + (size_t)(n * 2 + cb) * IMGB + (size_t)px * ROWB;
#pragma unroll
    for (int h = 0; h < 4; ++h) {
        short8 o;
#pragma unroll
        for (int j = 0; j < 8; ++j) o[j] = f2bs(src[(h * 8 + j) * 256]);
        *(short8*)(drow + h * 16) = o;
    }
}

// ---------------------------------------------------------------------------
// MFMA implicit-GEMM conv + fused instance-norm + leaky-relu.
// A: compact DMA images (no halo). Halo handled in compute: wave-uniform
// py-range skip (0-contribution MFMAs elided -> bit-identical) + zero-row
// cndmask for per-lane x edges. B: dy-grouped, double-buffered DMA.
// LDS 49280 B (K=3) -> 3 blocks/CU.
// MODE 0: norm+act -> pm-bf16 outb (rowB 72).  MODE 1: norm+act, outf += (cm f32).
// MODE 3: norm+act -> outf (cm f32).  MODE 2 (conv1b): n0<128 raw -> out_s
// (pm-bf16 rowB 64); 128..255 norm+act -> outf nt (new_p); else raw -> out_o.
// GATHER: chunks {0,1}=obj[s], {2,3}=pred bcast (register fill), {4,5}=obj[o].
// ---------------------------------------------------------------------------
template<int K, int MODE, bool GATHER, int NCB>
__global__ __launch_bounds__(TPB, 3) void mconv_kernel(
    const bf16* __restrict__ inA,      // DMA-image tensor
    const float* __restrict__ pred_vecs,
    const int*  __restrict__ edges,
    const bf16* __restrict__ wbf,
    const float* __restrict__ bfp,
    float* __restrict__ outf,
    bf16*  __restrict__ outb,
    bf16*  __restrict__ out_s,
    bf16*  __restrict__ out_o,
    int nc)                            // Cin/32
{
    constexpr int NGR  = (K == 3) ? 3 : 1;
    constexpr int GRPB = (K == 3) ? 14336 : 5120;
    constexpr int ASHS = (K == 3) ? 9280 : 9216;    // shorts
    constexpr int ZR   = 9216;                       // zero row base (shorts)

    __shared__ __align__(16) short Ash[ASHS];
    __shared__ __align__(16) short Bsh[2][GRPB / 2];
    __shared__ float redS[256], redS2[256];

    const int tid  = threadIdx.x;
    const int lane = tid & 63;
    const int wv   = tid >> 6;
    const int quad = lane >> 4;
    const int l16  = lane & 15;

    // XCD-aware swizzle, image-major units
    const int d = blockIdx.x;
    const int u = (d & 7) * (gridDim.x >> 3) + (d >> 3);
    const int n  = u / NCB;
    const int n0 = (u - n * NCB) * 64;

    if (K == 3 && tid < 36) Ash[ZR + tid] = 0;   // zero row (x-edge reads)

    float4v acc[4][4];
#pragma unroll
    for (int nt = 0; nt < 4; ++nt) {
        float b = bfp[n0 + nt * 16 + l16];
#pragma unroll
        for (int mt = 0; mt < 4; ++mt) acc[mt][nt] = float4v{b, b, b, b};
    }

    int s_idx = 0, o_idx = 0;
    if (GATHER) { s_idx = edges[2 * n]; o_idx = edges[2 * n + 1]; }

    const char* wimg = (const char*)wbf + (size_t)((n0 >> 6) * nc) * (NGR * GRPB);

    for (int cc = 0; cc < nc; ++cc) {
        __syncthreads();
        // ---- stage A ----
        if (GATHER && (cc == 2 || cc == 3)) {
            // pred broadcast: every thread fills its pixel row from registers
            const float* pv = pred_vecs + n * 64 + (cc - 2) * 32;
            short* row = &Ash[tid * 36];
#pragma unroll
            for (int h = 0; h < 4; ++h) {
                short8 o;
#pragma unroll
                for (int j = 0; j < 8; ++j) o[j] = f2bs(pv[h * 8 + j]);
                *(short8*)&row[h * 8] = o;
            }
        } else {
            int img;
            if (GATHER) img = (cc < 2) ? (s_idx * 2 + cc) : (o_idx * 2 + cc - 4);
            else        img = n * nc + cc;
            const char* asrc = (const char*)inA + (size_t)img * IMGB;
            for (int k = wv; k < 18; k += 4)
                gl_lds16(asrc + (k << 10) + (lane << 4), (char*)Ash + (k << 10));
        }
        // ---- stage B group 0 ----
        const char* bimg = wimg + (size_t)cc * (NGR * GRPB);
        for (int k = wv; k < GRPB / 1024; k += 4)
            gl_lds16(bimg + (k << 10) + (lane << 4), (char*)Bsh[0] + (k << 10));
        __syncthreads();

        // ---- compute per dy-group, prefetching next group ----
#pragma unroll 1
        for (int g = 0; g < NGR; ++g) {
            if (g + 1 < NGR) {
                const char* bs2 = bimg + (size_t)(g + 1) * GRPB;
                for (int k = wv; k < GRPB / 1024; k += 4)
                    gl_lds16(bs2 + (k << 10) + (lane << 4),
                             (char*)Bsh[(g + 1) & 1] + (k << 10));
            }
            const short* Bb = Bsh[g & 1];
#pragma unroll
            for (int t = 0; t < ((K == 3) ? 3 : 1); ++t) {
                short8 bfr[4];
#pragma unroll
                for (int nt = 0; nt < 4; ++nt)
                    bfr[nt] = *(const short8*)&Bb[(t * 64 + nt * 16 + l16) * 36 + (quad << 3)];
                if (K == 3) {
                    const bool ex = (t == 0 && l16 == 0) || (t == 2 && l16 == 15);
#pragma unroll
                    for (int mt = 0; mt < 4; ++mt) {
                        const int py = (wv << 2) + mt + g - 1;   // dy == g
                        if ((unsigned)py < 16u) {                // uniform; skipped = +0
                            int ad = ((py << 4) + l16 + t - 1) * 36 + (quad << 3);
                            if (ex) ad = ZR + (quad << 3);       // x out of image -> zeros
                            short8 afr = *(const short8*)&Ash[ad];
#pragma unroll
                            for (int nt = 0; nt < 4; ++nt)
                                acc[mt][nt] = __builtin_amdgcn_mfma_f32_16x16x32_bf16(
                                    afr, bfr[nt], acc[mt][nt], 0, 0, 0);
                        }
                    }
                } else {
#pragma unroll
                    for (int mt = 0; mt < 4; ++mt) {
                        short8 afr = *(const short8*)&Ash[((wv << 6) + mt * 16 + l16) * 36 + (quad << 3)];
#pragma unroll
                        for (int nt = 0; nt < 4; ++nt)
                            acc[mt][nt] = __builtin_amdgcn_mfma_f32_16x16x32_bf16(
                                afr, bfr[nt], acc[mt][nt], 0, 0, 0);
                    }
                }
            }
            if (g + 1 < NGR) __syncthreads();
        }
    }

    // ---------------- epilogue ----------------
    const bool do_norm = (MODE == 2) ? (n0 >= 128 && n0 < 256) : true;
    float mean[4], rstd[4];
    if (do_norm) {
#pragma unroll
        for (int nt = 0; nt < 4; ++nt) {
            float s = 0.f, s2 = 0.f;
#pragma unroll
            for (int mt = 0; mt < 4; ++mt)
#pragma unroll
                for (int r = 0; r < 4; ++r) {
                    float v = acc[mt][nt][r];
                    s += v; s2 += v * v;
                }
            s  += __shfl_xor(s, 16, 64);  s  += __shfl_xor(s, 32, 64);
            s2 += __shfl_xor(s2, 16, 64); s2 += __shfl_xor(s2, 32, 64);
            if (quad == 0) {
                redS [wv * 64 + nt * 16 + l16] = s;
                redS2[wv * 64 + nt * 16 + l16] = s2;
            }
        }
        __syncthreads();
#pragma unroll
        for (int nt = 0; nt < 4; ++nt) {
            int c = nt * 16 + l16;
            float s  = redS [c] + redS [64 + c] + redS [128 + c] + redS [192 + c];
            float s2 = redS2[c] + redS2[64 + c] + redS2[128 + c] + redS2[192 + c];
            float m  = s * (1.f / 256.f);
            float var = s2 * (1.f / 256.f) - m * m;
            mean[nt] = m;
            rstd[nt] = rsqrtf(var + 1e-5f);
        }
    }

    const bool cmpath = (MODE == 1) || (MODE == 3) ||
                        (MODE == 2 && n0 >= 128 && n0 < 256);
    if (cmpath) {
        // channel-major f32: Tb[16 ch][260] transpose, float4 coalesced stores
        float* Tb = (float*)Ash;
        float* base = outf + (size_t)n * 128 * 256;
#pragma unroll 1
        for (int nt = 0; nt < 4; ++nt) {
            __syncthreads();
#pragma unroll
            for (int mt = 0; mt < 4; ++mt)
#pragma unroll
                for (int r = 0; r < 4; ++r) {
                    float v = acc[mt][nt][r];
                    if (do_norm) {
                        v = (v - mean[nt]) * rstd[nt];
                        v = (v >= 0.f) ? v : 0.1f * v;
                    }
                    Tb[l16 * 260 + (wv << 6) + mt * 16 + (quad << 2) + r] = v;
                }
            __syncthreads();
            const int choff = ((MODE == 2) ? (n0 - 128) : n0) + nt * 16;
#pragma unroll
            for (int s = 0; s < 4; ++s) {
                const int ch = (s << 2) + wv;
                float4v v = *(const float4v*)&Tb[ch * 260 + (lane << 2)];
                float4v* dst = (float4v*)(base + (size_t)(choff + ch) * 256) + lane;
                if (MODE == 1) { v = v + *dst; *dst = v; }
                else if (MODE == 2) __builtin_nontemporal_store(v, dst);
                else *dst = v;
            }
        }
    } else {
        // pixel-major bf16 -> DMA-image tensors. T2[256 px][18] f32.
        bf16* timg; int rowb, chbase;
        if (MODE == 0)      { timg = (bf16*)((char*)outb + (size_t)n * 4 * IMGB); rowb = 72; chbase = n0; }
        else if (n0 < 128)  { timg = (bf16*)((char*)out_s + (size_t)n * 4 * 16384); rowb = 64; chbase = n0; }
        else                { timg = (bf16*)((char*)out_o + (size_t)n * 4 * 16384); rowb = 64; chbase = n0 - 256; }
        float* T2 = (float*)Ash;
#pragma unroll 1
        for (int nt = 0; nt < 4; ++nt) {
            __syncthreads();
#pragma unroll
            for (int mt = 0; mt < 4; ++mt)
#pragma unroll
                for (int r = 0; r < 4; ++r) {
                    float v = acc[mt][nt][r];
                    if (do_norm) {
                        v = (v - mean[nt]) * rstd[nt];
                        v = (v >= 0.f) ? v : 0.1f * v;
                    }
                    T2[((wv << 6) + mt * 16 + (quad << 2) + r) * 18 + l16] = v;
                }
            __syncthreads();
            const int ch = chbase + nt * 16;
            const int cb = ch >> 5, ci0 = ch & 31;   // 0 or 16
            const float* src = &T2[tid * 18];
            short8 o0, o1;
#pragma unroll
            for (int j = 0; j < 8; ++j) { o0[j] = f2bs(src[j]); o1[j] = f2bs(src[8 + j]); }
            char* dst = (char*)timg + (size_t)cb * (256 * rowb) + (size_t)tid * rowb + ci0 * 2;
            *(short8*)dst = o0;
            *(short8*)(dst + 16) = o1;
        }
    }
}

// ---------------------------------------------------------------------------
// Deterministic segment-mean pooling over pm tensors (rowB 64) -> pooled image.
// ---------------------------------------------------------------------------
__global__ __launch_bounds__(TPB) void pool_kernel(
    const int* __restrict__ edges,
    const bf16* __restrict__ new_s,
    const bf16* __restrict__ new_o,
    bf16* __restrict__ pooled)
{
    const int ob  = blockIdx.x;
    const int tid = threadIdx.x;
    __shared__ int list[2048];
    __shared__ int cnt;
    if (tid == 0) cnt = 0;
    __syncthreads();
    for (int t = tid; t < 1024; t += TPB) {
        int si = edges[2 * t], oi = edges[2 * t + 1];
        if (si == ob) { int p = atomicAdd(&cnt, 1); list[p] = t * 2; }
        if (oi == ob) { int p = atomicAdd(&cnt, 1); list[p] = t * 2 + 1; }
    }
    __syncthreads();
    const int c = cnt;
    const float inv = 1.f / fmaxf((float)c, 1.f);
    for (int task = tid; task < 1024; task += TPB) {   // (cb, px)
        const int cb = task >> 8, px = task & 255;
        float s[32];
#pragma unroll
        for (int j = 0; j < 32; ++j) s[j] = 0.f;
        for (int m = 0; m < c; ++m) {
            int ent = list[m];
            int nn  = ent >> 1;
            const char* src = (const char*)((ent & 1) ? new_o : new_s)
                + ((size_t)(nn * 4 + cb) * 256 + px) * 64;
#pragma unroll
            for (int h = 0; h < 4; ++h) {
                short8 v = *(const short8*)(src + h * 16);
#pragma unroll
                for (int j = 0; j < 8; ++j) s[h * 8 + j] += bs2f(v[j]);
            }
        }
        char* drow = (char*)pooled + (size_t)(ob * 4 + cb) * IMGB + (size_t)px * ROWB;
#pragma unroll
        for (int h = 0; h < 4; ++h) {
            short8 o;
#pragma unroll
            for (int j = 0; j < 8; ++j) o[j] = f2bs(s[h * 8 + j] * inv);
            *(short8*)(drow + h * 16) = o;
        }
    }
}

// ---------------------------------------------------------------------------
extern "C" void kernel_launch(void* const* d_in, const int* in_sizes, int n_in,
                              void* d_out, int out_size, void* d_ws, size_t ws_size,
                              hipStream_t stream) {
    const float* obj_maps  = (const float*)d_in[0];
    const float* pred_vecs = (const float*)d_in[1];
    const int*   edges     = (const int*)d_in[2];
    const float* w1a = (const float*)d_in[4];  const float* b1a = (const float*)d_in[5];
    const float* w1b = (const float*)d_in[6];  const float* b1b = (const float*)d_in[7];
    const float* w2a = (const float*)d_in[8];  const float* b2a = (const float*)d_in[9];
    const float* w2b = (const float*)d_in[10]; const float* b2b = (const float*)d_in[11];
    const float* woa = (const float*)d_in[12]; const float* boa = (const float*)d_in[13];
    const float* wob = (const float*)d_in[14]; const float* bob = (const float*)d_in[15];

    float* out = (float*)d_out;                       // [new_obj | new_p] f32
    const size_t NP_OFF = (size_t)512 * 128 * 256;

    char* ws = (char*)d_ws;
    size_t off = 0;
    auto alloc = [&](size_t bytes) -> char* {
        char* p = ws + off;
        off += (bytes + 255) & ~(size_t)255;
        return p;
    };
    // A: t1 (1024 img x 4 cb); later pooled [0:37.75M) + u1 [37.75M:75.5M)
    char* A = alloc((size_t)1024 * 4 * IMGB);         // 75.5 MB
    // B: new_o (1024 x 4 x 16384); later v1 [0:37.75M)
    char* B = alloc((size_t)1024 * 4 * 16384);        // 67.1 MB
    bf16* obj_dma = (bf16*)alloc((size_t)512 * 2 * IMGB);  // 18.9 MB
    auto wsz = [](int Cout, int Cin, int K) -> size_t {
        return (size_t)(Cout / 64) * (Cin / 32) * ((K == 3) ? 3 * 14336 : 5120);
    };
    bf16* wb1a = (bf16*)alloc(wsz(128, 192, 3));
    bf16* wb1b = (bf16*)alloc(wsz(384, 128, 3));
    bf16* wb2a = (bf16*)alloc(wsz(128, 128, 3));
    bf16* wb2b = (bf16*)alloc(wsz(128, 128, 1));
    bf16* wboa = (bf16*)alloc(wsz(128,  64, 3));
    bf16* wbob = (bf16*)alloc(wsz(128, 128, 1));
    // total ~164 MB  (< 201.3 MB proven available)

    bf16* t1     = (bf16*)A;
    bf16* pooled = (bf16*)A;                              // after conv1b
    bf16* u1     = (bf16*)(A + (size_t)512 * 4 * IMGB);   // after pool
    bf16* new_o  = (bf16*)B;
    bf16* v1     = (bf16*)B;                              // after pool
    bf16* new_s  = (bf16*)out;                            // d_out new_obj region as scratch

    // ---- prep ----
    auto wx = [&](const float* w, bf16* dw, int Cout, int Cin, int K) {
        int total8 = (int)(wsz(Cout, Cin, K) / 16);
        wxform_kernel<<<dim3((total8 + TPB - 1) / TPB), dim3(TPB), 0, stream>>>(
            w, dw, Cin, K, total8);
    };
    wx(w1a, wb1a, 128, 192, 3);
    wx(w1b, wb1b, 384, 128, 3);
    wx(w2a, wb2a, 128, 128, 3);
    wx(w2b, wb2b, 128, 128, 1);
    wx(woa, wboa, 128,  64, 3);
    wx(wob, wbob, 128, 128, 1);
    objcvt_kernel<<<dim3(1024), dim3(TPB), 0, stream>>>(obj_maps, obj_dma);

    // conv1a: gather 192 -> 128, 3x3, norm+act -> t1 (pm)
    mconv_kernel<3, 0, true, 2><<<dim3(2048), dim3(TPB), 0, stream>>>(
        obj_dma, pred_vecs, edges, wb1a, b1a, nullptr, t1, nullptr, nullptr, 6);

    // conv1b: t1 128 -> 384, 3x3; s->new_s(d_out scratch), mid->new_p, o->new_o
    mconv_kernel<3, 2, false, 6><<<dim3(6144), dim3(TPB), 0, stream>>>(
        t1, nullptr, nullptr, wb1b, b1b, out + NP_OFF, nullptr, new_s, new_o, 4);

    // pool -> pooled (overlays t1)
    pool_kernel<<<dim3(512), dim3(TPB), 0, stream>>>(edges, new_s, new_o, pooled);

    // conv2a: pooled 128 -> 128, 3x3, norm+act -> u1 (pm)
    mconv_kernel<3, 0, false, 2><<<dim3(1024), dim3(TPB), 0, stream>>>(
        pooled, nullptr, nullptr, wb2a, b2a, nullptr, u1, nullptr, nullptr, 4);

    // convoa: obj 64 -> 128, 3x3, norm+act -> v1 (pm, overlays new_o)
    mconv_kernel<3, 0, false, 2><<<dim3(1024), dim3(TPB), 0, stream>>>(
        obj_dma, nullptr, nullptr, wboa, boa, nullptr, v1, nullptr, nullptr, 2);

    // conv2b: u1 128 -> 128, 1x1, norm+act -> d_out new_obj (overwrites scratch)
    mconv_kernel<1, 3, false, 2><<<dim3(1024), dim3(TPB), 0, stream>>>(
        u1, nullptr, nullptr, wb2b, b2b, out, nullptr, nullptr, nullptr, 4);

    // convob: v1 128 -> 128, 1x1, norm+act, d_out new_obj += 
    mconv_kernel<1, 1, false, 2><<<dim3(1024), dim3(TPB), 0, stream>>>(
        v1, nullptr, nullptr, wbob, bob, out, nullptr, nullptr, nullptr, 4);
}

// Round 7
// 2202.589 us; speedup vs baseline: 1.5487x; 1.5487x over previous
//
#include <hip/hip_runtime.h>
#include <hip/hip_bf16.h>

typedef __hip_bfloat16 bf16;
typedef __attribute__((ext_vector_type(8))) short short8;
typedef __attribute__((ext_vector_type(4))) short short4v;
typedef __attribute__((ext_vector_type(4))) float float4v;

#define TPB 256

__device__ __forceinline__ short f2bs(float v) {
    __hip_bfloat16 h = __float2bfloat16(v);
    return *reinterpret_cast<short*>(&h);
}
__device__ __forceinline__ float bs2f(short s) {
    union { unsigned u; float f; } c; c.u = ((unsigned)(unsigned short)s) << 16; return c.f;
}
__device__ __forceinline__ short ldbits(const bf16* p, size_t i)  { return ((const short*)p)[i]; }
__device__ __forceinline__ short ldbits(const float* p, size_t i) { return f2bs(p[i]); }
__device__ __forceinline__ void stf(float* p, size_t i, float v) { p[i] = v; }
__device__ __forceinline__ void stf(bf16* p, size_t i, float v)  { p[i] = __float2bfloat16(v); }

// async global->LDS DMA, 16B per lane; LDS dest = wave-uniform base + lane*16
__device__ __forceinline__ void gl_lds16(const void* g, void* l) {
    __builtin_amdgcn_global_load_lds(
        (const __attribute__((address_space(1))) void*)g,
        (__attribute__((address_space(3))) void*)l, 16, 0, 0);
}

// ---------------------------------------------------------------------------
// Weights -> bf16 DMA images [nb][cb][g(=dy)][GRPB]: rows (t*64+nn)*72B,
// 32 ci + 4 zero-pad shorts. K=3: 3 groups x 3 taps, GRPB=14336 (raw 13824).
// K=1: 1 group, GRPB=5120 (raw 4608). Linear copy target for global_load_lds.
// ---------------------------------------------------------------------------
__global__ void wxform_kernel(const float* __restrict__ w, bf16* __restrict__ dst,
                              int Cin, int K, int total8) {
    int i = blockIdx.x * TPB + threadIdx.x;
    if (i >= total8) return;
    const int NGR  = (K == 3) ? 3 : 1;
    const int GRPB = (K == 3) ? 14336 : 5120;
    const int RAWB = (K == 3) ? 13824 : 4608;
    const int TAPS = K * K;
    const int nc   = Cin >> 5;
    long b   = (long)i * 16;
    int  gl  = (int)(b / GRPB);
    int  off = (int)(b - (long)gl * GRPB);
    int  g   = gl % NGR; int t2 = gl / NGR;
    int  cb  = t2 % nc;  int nb = t2 / nc;
    short8 o;
#pragma unroll
    for (int j = 0; j < 8; ++j) {
        int ob = off + j * 2;
        float v = 0.f;
        if (ob < RAWB) {
            int r  = ob / 72;
            int ci = (ob - r * 72) >> 1;
            if (ci < 32) {
                int tap = g * ((K == 3) ? 3 : 1) + (r >> 6);
                int nn  = r & 63;
                v = w[((size_t)(nb * 64 + nn) * Cin + (cb * 32 + ci)) * TAPS + tap];
            }
        }
        o[j] = f2bs(v);
    }
    *(short8*)((char*)dst + b) = o;
}

// obj_maps f32 -> bf16 (one-time; numerics identical to per-conv f2bs staging)
__global__ void cvt_kernel(const float* __restrict__ src, bf16* __restrict__ dst, int n8) {
    int i = blockIdx.x * TPB + threadIdx.x;
    if (i >= n8) return;
    const float4v* s = (const float4v*)src;
    float4v a = s[i * 2], b = s[i * 2 + 1];
    short8 o;
#pragma unroll
    for (int j = 0; j < 4; ++j) { o[j] = f2bs(a[j]); o[4 + j] = f2bs(b[j]); }
    *(short8*)(dst + (size_t)i * 8) = o;
}

// ---------------------------------------------------------------------------
// MFMA implicit-GEMM conv (KxK, pad K/2) + fused instance-norm + leaky-relu.
// r4 structure; CS 40->36 + B dy-group double-buffer -> LDS 54KB, 3 blocks/CU.
// A staged per-thread (pixel tid) scalar cm loads -> short8 ds_write_b128.
// B staged per dy-group via global_load_lds of pre-padded weight images.
// Epilogue: f32 LDS transpose (TS=260), coalesced cm stores (short4/float4).
// MODE 0: norm+act -> out. MODE 1: norm+act, out += (f32).
// MODE 2 (conv1b): n0<128 raw->out_s(bf16); 128..255 norm+act->out(f32); else raw->out_o.
// GATHER: input = concat(obj[s], pred bcast, obj[o]) per edge.
// ---------------------------------------------------------------------------
template<int K, int MODE, bool GATHER, int NCB, typename TIN, typename TOUT>
__global__ __launch_bounds__(TPB, 3) void mconv_kernel(
    const TIN* __restrict__ in,
    const float* __restrict__ pred_vecs,
    const int*  __restrict__ edges,
    const bf16* __restrict__ wbf,    // [nb][cb][g][GRPB] bf16 group images
    const float* __restrict__ bfp,   // (Cout) f32
    TOUT* __restrict__ out,
    bf16* __restrict__ out_s,
    bf16* __restrict__ out_o,
    int Cin, int Cout)
{
    constexpr int P    = K / 2;
    constexpr int W    = 16 + 2 * P;            // padded tile width
    constexpr int NGR  = (K == 3) ? 3 : 1;      // dy groups
    constexpr int TPG  = (K == 3) ? 3 : 1;      // taps (dx) per group
    constexpr int GRPB = (K == 3) ? 14336 : 5120;
    constexpr int NBUF = (K == 3) ? 2 : 1;
    constexpr int CS   = 36;                    // channel stride: 72B rows, 16 bank starts

    __shared__ __align__(16) short Ash[W * W * CS];
    __shared__ __align__(16) short Bsh[NBUF][GRPB / 2];
    __shared__ float redS[256], redS2[256];

    const int tid  = threadIdx.x;
    const int lane = tid & 63;
    const int wv   = tid >> 6;
    const int quad = lane >> 4;
    const int l16  = lane & 15;

    // XCD-aware swizzle: each of 8 XCDs takes a contiguous, image-major chunk.
    const int d = blockIdx.x;
    const int u = (d & 7) * (gridDim.x >> 3) + (d >> 3);
    const int n  = u / NCB;
    const int n0 = (u - n * NCB) * 64;

    // zero A buffer once (border + pad columns stay 0 forever)
    for (int i = tid; i < W * W * CS / 2; i += TPB) ((int*)Ash)[i] = 0;

    float4v acc[4][4];
#pragma unroll
    for (int nt = 0; nt < 4; ++nt) {
        float b = bfp[n0 + nt * 16 + l16];
#pragma unroll
        for (int mt = 0; mt < 4; ++mt) acc[mt][nt] = float4v{b, b, b, b};
    }

    int s_idx = 0, o_idx = 0;
    if (GATHER) { s_idx = edges[2 * n]; o_idx = edges[2 * n + 1]; }

    const int y0 = tid >> 4, x0 = tid & 15;
    const int abase = ((y0 + P) * W + (x0 + P)) * CS;
    const int nc = Cin >> 5;

    for (int cc = 0; cc < nc; ++cc) {
        __syncthreads();

        // ---- stage A: 32 ch x 256 pix, short8-packed, one b128 write / 8ch ----
#pragma unroll
        for (int c8 = 0; c8 < 4; ++c8) {
            short8 pk;
#pragma unroll
            for (int j = 0; j < 8; ++j) {
                const int gc = cc * 32 + c8 * 8 + j;
                short s;
                if (GATHER) {
                    if (gc < 64)
                        s = ldbits(in, (size_t)s_idx * 16384 + (size_t)gc * 256 + tid);
                    else if (gc < 128)
                        s = f2bs(pred_vecs[n * 64 + (gc - 64)]);
                    else
                        s = ldbits(in, (size_t)o_idx * 16384 + (size_t)(gc - 128) * 256 + tid);
                } else {
                    s = ldbits(in, ((size_t)n * Cin + gc) * 256 + tid);
                }
                pk[j] = s;
            }
            *(short8*)&Ash[abase + c8 * 8] = pk;
        }

        // ---- stage B group 0 via DMA ----
        const char* bimg = (const char*)wbf +
            (size_t)((n0 >> 6) * nc + cc) * (NGR * GRPB);
        for (int k = wv; k < GRPB / 1024; k += 4)
            gl_lds16(bimg + (k << 10) + (lane << 4), (char*)Bsh[0] + (k << 10));
        __syncthreads();   // A writes + B0 DMA drained

        // ---- compute per dy-group, prefetching next group ----
#pragma unroll 1
        for (int g = 0; g < NGR; ++g) {
            if (NGR > 1 && g + 1 < NGR) {
                const char* bs2 = bimg + (size_t)(g + 1) * GRPB;
                for (int k = wv; k < GRPB / 1024; k += 4)
                    gl_lds16(bs2 + (k << 10) + (lane << 4),
                             (char*)Bsh[(g + 1) & (NBUF - 1)] + (k << 10));
            }
            const short* Bb = Bsh[(NBUF > 1) ? (g & 1) : 0];
#pragma unroll
            for (int t = 0; t < TPG; ++t) {
                short8 bfr[4];
#pragma unroll
                for (int nt = 0; nt < 4; ++nt)
                    bfr[nt] = *(const short8*)&Bb[(t * 64 + nt * 16 + l16) * CS + quad * 8];
#pragma unroll
                for (int mt = 0; mt < 4; ++mt) {
                    const int m = (wv << 6) + mt * 16 + l16;
                    const int pix = ((m >> 4) + g) * W + ((m & 15) + t);  // dy=g, dx=t
                    short8 afr = *(const short8*)&Ash[pix * CS + quad * 8];
#pragma unroll
                    for (int nt = 0; nt < 4; ++nt)
                        acc[mt][nt] = __builtin_amdgcn_mfma_f32_16x16x32_bf16(
                            afr, bfr[nt], acc[mt][nt], 0, 0, 0);
                }
            }
            if (NGR > 1 && g + 1 < NGR) __syncthreads();
        }
    }

    // ---------------- epilogue ----------------
    const bool do_norm = (MODE == 2) ? (n0 >= 128 && n0 < 256) : true;
    float mean[4], rstd[4];
    if (do_norm) {
#pragma unroll
        for (int nt = 0; nt < 4; ++nt) {
            float s = 0.f, s2 = 0.f;
#pragma unroll
            for (int mt = 0; mt < 4; ++mt)
#pragma unroll
                for (int r = 0; r < 4; ++r) {
                    float v = acc[mt][nt][r];
                    s += v; s2 += v * v;
                }
            s  += __shfl_xor(s, 16, 64);  s  += __shfl_xor(s, 32, 64);
            s2 += __shfl_xor(s2, 16, 64); s2 += __shfl_xor(s2, 32, 64);
            if (quad == 0) {
                redS [wv * 64 + nt * 16 + l16] = s;
                redS2[wv * 64 + nt * 16 + l16] = s2;
            }
        }
        __syncthreads();
#pragma unroll
        for (int nt = 0; nt < 4; ++nt) {
            int c = nt * 16 + l16;
            float s  = redS [c] + redS [64 + c] + redS [128 + c] + redS [192 + c];
            float s2 = redS2[c] + redS2[64 + c] + redS2[128 + c] + redS2[192 + c];
            float m  = s * (1.f / 256.f);
            float var = s2 * (1.f / 256.f) - m * m;
            mean[nt] = m;
            rstd[nt] = rsqrtf(var + 1e-5f);
        }
    }

    // LDS transpose (TS=260 dwords) + coalesced cm stores.
    float* Tb = (float*)Ash;
    constexpr int TS = 260;

    auto store_b = [&](bf16* base, int ch_off) {
#pragma unroll
        for (int s = 0; s < 4; ++s) {
            const int ch = (s << 2) + wv;
            const float* src = &Tb[ch * TS + (lane << 2)];
            short4v o4;
#pragma unroll
            for (int j = 0; j < 4; ++j) o4[j] = f2bs(src[j]);
            *(short4v*)(base + (size_t)(ch_off + ch) * 256 + (lane << 2)) = o4;
        }
    };
    auto store_f = [&](float* base, int ch_off, bool rmw) {
#pragma unroll
        for (int s = 0; s < 4; ++s) {
            const int ch = (s << 2) + wv;
            float4v v = *(const float4v*)&Tb[ch * TS + (lane << 2)];
            float4v* dst = (float4v*)(base + (size_t)(ch_off + ch) * 256) + lane;
            if (rmw) v = v + *dst;
            *dst = v;
        }
    };

#pragma unroll 1
    for (int nt = 0; nt < 4; ++nt) {
        __syncthreads();
#pragma unroll
        for (int mt = 0; mt < 4; ++mt)
#pragma unroll
            for (int r = 0; r < 4; ++r) {
                float v = acc[mt][nt][r];
                if (do_norm) {
                    v = (v - mean[nt]) * rstd[nt];
                    v = (v >= 0.f) ? v : 0.1f * v;
                }
                Tb[l16 * TS + (wv << 6) + mt * 16 + (quad << 2) + r] = v;
            }
        __syncthreads();
        const int nt16 = nt * 16;
        if (MODE == 2) {
            if (n0 < 128)
                store_b(out_s + (size_t)n * 128 * 256, n0 + nt16);
            else if (n0 < 256)
                store_f((float*)out + (size_t)n * 128 * 256, (n0 - 128) + nt16, false);
            else
                store_b(out_o + (size_t)n * 128 * 256, (n0 - 256) + nt16);
        } else if (MODE == 1) {
            store_f((float*)out + (size_t)n * Cout * 256, n0 + nt16, true);
        } else {
            if constexpr (sizeof(TOUT) == 2)
                store_b((bf16*)out + (size_t)n * Cout * 256, n0 + nt16);
            else
                store_f((float*)out + (size_t)n * Cout * 256, n0 + nt16, false);
        }
    }
}

// ---------------------------------------------------------------------------
// Deterministic segment-mean pooling, short8-vectorized (r4 verbatim).
// ---------------------------------------------------------------------------
__global__ __launch_bounds__(TPB) void pool_kernel(
    const int* __restrict__ edges,
    const bf16* __restrict__ new_s,
    const bf16* __restrict__ new_o,
    bf16* __restrict__ pooled)
{
    const int ob  = blockIdx.x;
    const int tid = threadIdx.x;
    __shared__ int list[2048];
    __shared__ int cnt;
    if (tid == 0) cnt = 0;
    __syncthreads();
    for (int t = tid; t < 1024; t += TPB) {
        int si = edges[2 * t], oi = edges[2 * t + 1];
        if (si == ob) { int p = atomicAdd(&cnt, 1); list[p] = t * 2; }
        if (oi == ob) { int p = atomicAdd(&cnt, 1); list[p] = t * 2 + 1; }
    }
    __syncthreads();
    const int c = cnt;
    const float inv = 1.f / fmaxf((float)c, 1.f);
    for (int e8 = tid; e8 < 4096; e8 += TPB) {          // 32768 elems / 8
        float s[8] = {0.f, 0.f, 0.f, 0.f, 0.f, 0.f, 0.f, 0.f};
        for (int m = 0; m < c; ++m) {
            int ent = list[m];
            int nn  = ent >> 1;
            const bf16* src = (ent & 1) ? new_o : new_s;
            short8 v = *(const short8*)(src + (size_t)nn * 32768 + (size_t)e8 * 8);
#pragma unroll
            for (int j = 0; j < 8; ++j) s[j] += bs2f(v[j]);
        }
        short8 o;
#pragma unroll
        for (int j = 0; j < 8; ++j) o[j] = f2bs(s[j] * inv);
        *(short8*)(pooled + (size_t)ob * 32768 + (size_t)e8 * 8) = o;
    }
}

// ---------------------------------------------------------------------------
extern "C" void kernel_launch(void* const* d_in, const int* in_sizes, int n_in,
                              void* d_out, int out_size, void* d_ws, size_t ws_size,
                              hipStream_t stream) {
    const float* obj_maps  = (const float*)d_in[0];   // (512,64,16,16) f32
    const float* pred_vecs = (const float*)d_in[1];   // (1024,64) f32
    const int*   edges     = (const int*)d_in[2];     // (1024,2) i32
    const float* w1a = (const float*)d_in[4];  const float* b1a = (const float*)d_in[5];
    const float* w1b = (const float*)d_in[6];  const float* b1b = (const float*)d_in[7];
    const float* w2a = (const float*)d_in[8];  const float* b2a = (const float*)d_in[9];
    const float* w2b = (const float*)d_in[10]; const float* b2b = (const float*)d_in[11];
    const float* woa = (const float*)d_in[12]; const float* boa = (const float*)d_in[13];
    const float* wob = (const float*)d_in[14]; const float* bob = (const float*)d_in[15];

    float* out = (float*)d_out;                       // [new_obj | new_p] f32
    const size_t NP_OFF = (size_t)512 * 128 * 256;

    char* ws = (char*)d_ws;
    size_t off = 0;
    auto alloc = [&](size_t bytes) -> char* {
        char* p = ws + off;
        off += (bytes + 255) & ~(size_t)255;
        return p;
    };
    const size_t SZ_T = (size_t)1024 * 128 * 256 * 2;   // 67 MB
    char* Bt1   = alloc(SZ_T);
    char* Bnews = alloc(SZ_T);
    char* Bnewo = alloc(SZ_T);
    // group-padded weight images: (Cout/64)*(Cin/32)*(NGR*GRPB)
    auto wsz = [](int Cout, int Cin, int K) -> size_t {
        return (size_t)(Cout / 64) * (Cin / 32) * ((K == 3) ? 3 * 14336 : 5120);
    };
    bf16* wb1a = (bf16*)alloc(wsz(128, 192, 3));
    bf16* wb1b = (bf16*)alloc(wsz(384, 128, 3));
    bf16* wb2a = (bf16*)alloc(wsz(128, 128, 3));
    bf16* wb2b = (bf16*)alloc(wsz(128, 128, 1));
    bf16* wboa = (bf16*)alloc(wsz(128,  64, 3));
    bf16* wbob = (bf16*)alloc(wsz(128, 128, 1));
    // optional bf16 obj_maps cache (guarded by ws_size; fall back to f32 reads)
    const size_t OBJ_SZ = (size_t)512 * 64 * 256 * 2;   // 16.8 MB
    bf16* obj_bf = (bf16*)alloc(OBJ_SZ);
    const bool use_objbf = (off <= ws_size);

    bf16* t1     = (bf16*)Bt1;
    bf16* new_s  = (bf16*)Bnews;
    bf16* new_o  = (bf16*)Bnewo;
    bf16* pooled = (bf16*)Bt1;                                   // t1 dead after conv1b
    bf16* u1     = (bf16*)(Bt1 + (size_t)512 * 128 * 256 * 2);
    bf16* v1     = (bf16*)Bnews;                                 // new_s dead after pool

    // ---- one-time prep: weights -> group-padded bf16 images; obj_maps -> bf16 ----
    auto wx = [&](const float* w, bf16* dw, int Cout, int Cin, int K) {
        int total8 = (int)(wsz(Cout, Cin, K) / 16);
        wxform_kernel<<<dim3((total8 + TPB - 1) / TPB), dim3(TPB), 0, stream>>>(
            w, dw, Cin, K, total8);
    };
    wx(w1a, wb1a, 128, 192, 3);
    wx(w1b, wb1b, 384, 128, 3);
    wx(w2a, wb2a, 128, 128, 3);
    wx(w2b, wb2b, 128, 128, 1);
    wx(woa, wboa, 128,  64, 3);
    wx(wob, wbob, 128, 128, 1);
    if (use_objbf)
        cvt_kernel<<<dim3(4096), dim3(TPB), 0, stream>>>(obj_maps, obj_bf, 512 * 64 * 256 / 8);

    // conv1a: gather(192) -> 128, 3x3, norm+act -> t1 (bf16)
    if (use_objbf)
        mconv_kernel<3, 0, true, 2, bf16, bf16><<<dim3(2048), dim3(TPB), 0, stream>>>(
            obj_bf, pred_vecs, edges, wb1a, b1a, t1, nullptr, nullptr, 192, 128);
    else
        mconv_kernel<3, 0, true, 2, float, bf16><<<dim3(2048), dim3(TPB), 0, stream>>>(
            obj_maps, pred_vecs, edges, wb1a, b1a, t1, nullptr, nullptr, 192, 128);

    // conv1b: t1 128 -> 384, 3x3; split new_s / new_p(norm+act, f32 d_out) / new_o
    mconv_kernel<3, 2, false, 6, bf16, float><<<dim3(6144), dim3(TPB), 0, stream>>>(
        t1, nullptr, nullptr, wb1b, b1b, out + NP_OFF, new_s, new_o, 128, 384);

    // segment-mean pooling -> pooled (512,128,16,16) bf16
    pool_kernel<<<dim3(512), dim3(TPB), 0, stream>>>(edges, new_s, new_o, pooled);

    // conv2a: pooled 128 -> 128, 3x3, norm+act -> u1 (bf16)
    mconv_kernel<3, 0, false, 2, bf16, bf16><<<dim3(1024), dim3(TPB), 0, stream>>>(
        pooled, nullptr, nullptr, wb2a, b2a, u1, nullptr, nullptr, 128, 128);

    // conv2b: u1 128 -> 128, 1x1, norm+act -> d_out[new_obj] (overwrite)
    mconv_kernel<1, 0, false, 2, bf16, float><<<dim3(1024), dim3(TPB), 0, stream>>>(
        u1, nullptr, nullptr, wb2b, b2b, out, nullptr, nullptr, 128, 128);

    // convoa: obj 64 -> 128, 3x3, norm+act -> v1 (bf16)
    if (use_objbf)
        mconv_kernel<3, 0, false, 2, bf16, bf16><<<dim3(1024), dim3(TPB), 0, stream>>>(
            obj_bf, nullptr, nullptr, wboa, boa, v1, nullptr, nullptr, 64, 128);
    else
        mconv_kernel<3, 0, false, 2, float, bf16><<<dim3(1024), dim3(TPB), 0, stream>>>(
            obj_maps, nullptr, nullptr, wboa, boa, v1, nullptr, nullptr, 64, 128);

    // convob: v1 128 -> 128, 1x1, norm+act, d_out[new_obj] += (f32)
    mconv_kernel<1, 1, false, 2, bf16, float><<<dim3(1024), dim3(TPB), 0, stream>>>(
        v1, nullptr, nullptr, wbob, bob, out, nullptr, nullptr, 128, 128);
}